// Round 1
// baseline (934.397 us; speedup 1.0000x reference)
//
#include <hip/hip_runtime.h>

typedef unsigned short u16;
typedef __attribute__((ext_vector_type(8))) short bf16x8;
typedef __attribute__((ext_vector_type(4))) float f32x4;
typedef __attribute__((ext_vector_type(4))) unsigned short u16x4;

#define MFMA16 __builtin_amdgcn_mfma_f32_16x16x32_bf16

#define HW   16384
#define NCLS 150
#define NPAD 160
#define CDIM 256

// LDS row strides chosen so byte stride % 32 == 16 (bank-spread) and % 16 == 0 (b128-aligned)
#define FT_STRIDE 264   // shorts per featT row (64 rows)  -> 528 B
#define FN_STRIDE 72    // shorts per featN row (256 rows) -> 144 B
#define S_STRIDE  65    // floats per S row   (160 rows)   -> 260 B
#define W_STRIDE  168   // shorts per w row   (64 rows)    -> 336 B
#define U_STRIDE  72    // shorts per U row   (160 rows)   -> 144 B

// K1 LDS layout (bytes)
#define K1_FTH 0
#define K1_FTL 33792
#define K1_S   67584
#define K1_STM 109184
#define K1_STL 109824
#define K1_LDS 110464
// K3 LDS layout (bytes)
#define K3_FTH 0        // aliased by w tile after S-GEMM
#define K3_FTL 33792
#define K3_FN  67584
#define K3_S   104448   // aliased by U tile after stats
#define K3_PM  146048
#define K3_MPV 148096
#define K3_PS  148352
#define K3_RZP 150400
#define K3_LDS 150656

// workspace offsets (bytes)
#define WS_CLSH 0
#define WS_CLSL 655360
#define WS_CLSWT 1310720
#define WS_MS 1966080
#define WS_LS 2129920
#define WS_MG 2293760
#define WS_RZ 2298880
#define WS_PART 2304000   // [8][32][256][160] f32 = 41,943,040 B

__device__ __forceinline__ u16 f2bf(float f){
  unsigned u = __float_as_uint(f);
  unsigned r = u + 0x7FFFu + ((u >> 16) & 1u);
  return (u16)(r >> 16);
}
__device__ __forceinline__ float bff(u16 h){
  return __uint_as_float(((unsigned)h) << 16);
}

// ---------------- K0: cls -> bf16 hi/lo (padded to 160 rows), cls_wT = (cls @ W_f^T)^T in bf16
__global__ __launch_bounds__(256) void k0(const float* __restrict__ cls, const float* __restrict__ Wf,
                                          u16* __restrict__ clsH, u16* __restrict__ clsL,
                                          u16* __restrict__ clsWT){
  int b = blockIdx.x / NPAD, n = blockIdx.x % NPAD, t = threadIdx.x;
  __shared__ float row[256];
  int bn = b*NPAD + n;
  if (n < NCLS){
    float v = cls[(b*NCLS + n)*CDIM + t];
    u16 h = f2bf(v);
    clsH[bn*CDIM + t] = h;
    clsL[bn*CDIM + t] = f2bf(v - bff(h));
    row[t] = v;
    __syncthreads();
    float acc = 0.f;
    const float* wr = Wf + t*CDIM;
    #pragma unroll 4
    for (int c = 0; c < 256; c += 4){
      acc += row[c]*wr[c] + row[c+1]*wr[c+1] + row[c+2]*wr[c+2] + row[c+3]*wr[c+3];
    }
    clsWT[(b*CDIM + t)*NPAD + n] = f2bf(acc);
  } else {
    clsH[bn*CDIM + t] = 0;
    clsL[bn*CDIM + t] = 0;
    clsWT[(b*CDIM + t)*NPAD + n] = 0;
  }
}

// stage a 256c x 64p feat subtile: featT (hi+lo, [p][c]) and optionally featN (hi, [c][p])
__device__ __forceinline__ void stage_feat(const float* __restrict__ featG, int p0,
                                           u16* ftH, u16* ftL, u16* fN, int t){
  int p = t & 63, cg = t >> 6;
  #pragma unroll
  for (int i = 0; i < 8; ++i){
    int c0 = (i*8 + cg)*4;
    const float* g0 = featG + c0*HW + p0 + p;
    float v0 = g0[0];
    float v1 = g0[HW];
    float v2 = g0[2*HW];
    float v3 = g0[3*HW];
    u16 h0 = f2bf(v0), h1 = f2bf(v1), h2 = f2bf(v2), h3 = f2bf(v3);
    u16x4 hv = {h0, h1, h2, h3};
    *(u16x4*)&ftH[p*FT_STRIDE + c0] = hv;
    u16x4 lv = {f2bf(v0 - bff(h0)), f2bf(v1 - bff(h1)), f2bf(v2 - bff(h2)), f2bf(v3 - bff(h3))};
    *(u16x4*)&ftL[p*FT_STRIDE + c0] = lv;
    if (fN){
      fN[(c0+0)*FN_STRIDE + p] = h0;
      fN[(c0+1)*FN_STRIDE + p] = h1;
      fN[(c0+2)*FN_STRIDE + p] = h2;
      fN[(c0+3)*FN_STRIDE + p] = h3;
    }
  }
}

// S[160][64] = cls[160][256] x featT^T via split-precision bf16 MFMA (hh + hl + lh)
__device__ __forceinline__ void s_gemm_tile(const u16* __restrict__ clsHb, const u16* __restrict__ clsLb,
                                            const u16* ftH, const u16* ftL, float* S, int t){
  int lane = t & 63, wv = t >> 6;
  int l15 = lane & 15, lk = lane >> 4;
  int nh = wv >> 2, pq = wv & 3;
  int nbase = nh*80;
  f32x4 acc[5];
  #pragma unroll
  for (int f = 0; f < 5; ++f) acc[f] = (f32x4){0.f, 0.f, 0.f, 0.f};
  #pragma unroll
  for (int kb = 0; kb < 8; ++kb){
    int ko = kb*32 + lk*8;
    bf16x8 bh = *(const bf16x8*)&ftH[(pq*16 + l15)*FT_STRIDE + ko];
    bf16x8 bl = *(const bf16x8*)&ftL[(pq*16 + l15)*FT_STRIDE + ko];
    #pragma unroll
    for (int f = 0; f < 5; ++f){
      int ai = (nbase + f*16 + l15)*CDIM + ko;
      bf16x8 ah = *(const bf16x8*)&clsHb[ai];
      bf16x8 al = *(const bf16x8*)&clsLb[ai];
      acc[f] = MFMA16(ah, bh, acc[f], 0, 0, 0);
      acc[f] = MFMA16(ah, bl, acc[f], 0, 0, 0);
      acc[f] = MFMA16(al, bh, acc[f], 0, 0, 0);
    }
  }
  #pragma unroll
  for (int f = 0; f < 5; ++f){
    #pragma unroll
    for (int r = 0; r < 4; ++r){
      S[(nbase + f*16 + lk*4 + r)*S_STRIDE + pq*16 + l15] = acc[f][r];
    }
  }
}

// ---------------- K1: per-(b, 512px chunk) row-stats (max / sumexp over p) for the cls softmax
__global__ __launch_bounds__(512) void k1(const float* __restrict__ feat,
                                          const u16* __restrict__ clsH, const u16* __restrict__ clsL,
                                          float* __restrict__ msOut, float* __restrict__ lsOut){
  extern __shared__ char sm[];
  u16*  ftH = (u16*)(sm + K1_FTH);
  u16*  ftL = (u16*)(sm + K1_FTL);
  float* S  = (float*)(sm + K1_S);
  float* stm = (float*)(sm + K1_STM);
  float* stl = (float*)(sm + K1_STL);
  int b = blockIdx.x >> 5, ch = blockIdx.x & 31, t = threadIdx.x;
  const float* featG = feat + b*(CDIM*HW);
  const u16* clsHb = clsH + b*NPAD*CDIM;
  const u16* clsLb = clsL + b*NPAD*CDIM;
  if (t < NPAD){ stm[t] = -3.0e38f; stl[t] = 0.f; }
  __syncthreads();
  for (int sub = 0; sub < 8; ++sub){
    int p0 = ch*512 + sub*64;
    stage_feat(featG, p0, ftH, ftL, (u16*)0, t);
    __syncthreads();
    s_gemm_tile(clsHb, clsLb, ftH, ftL, S, t);
    __syncthreads();
    if (t < NPAD){
      float m = stm[t], lacc = stl[t];
      const float* Sr = S + t*S_STRIDE;
      float rmax = -3.0e38f;
      #pragma unroll 8
      for (int p = 0; p < 64; ++p) rmax = fmaxf(rmax, Sr[p]);
      float mn = fmaxf(m, rmax);
      float s = 0.f;
      #pragma unroll 8
      for (int p = 0; p < 64; ++p) s += __expf(Sr[p] - mn);
      stl[t] = lacc * __expf(m - mn) + s;
      stm[t] = mn;
    }
    __syncthreads();
  }
  if (t < NPAD){
    msOut[(b*32 + ch)*NPAD + t] = stm[t];
    lsOut[(b*32 + ch)*NPAD + t] = stl[t];
  }
}

// ---------------- K2: reduce chunk stats -> global max, 1/Z per (b,n)
__global__ __launch_bounds__(256) void k2(const float* __restrict__ ms, const float* __restrict__ ls,
                                          float* __restrict__ m_g, float* __restrict__ rZ){
  int b = blockIdx.x, t = threadIdx.x;
  if (t < NPAD){
    float m = -3.0e38f;
    for (int s = 0; s < 32; ++s) m = fmaxf(m, ms[(b*32 + s)*NPAD + t]);
    float z = 0.f;
    for (int s = 0; s < 32; ++s) z += ls[(b*32 + s)*NPAD + t] * __expf(ms[(b*32 + s)*NPAD + t] - m);
    m_g[b*NPAD + t] = m;
    rZ[b*NPAD + t] = 1.0f / z;
  }
}

// ---------------- K3: fused main — S, pos softmax + pos-value GEMM -> out1, cls-value partials
__global__ __launch_bounds__(512) void k3(const float* __restrict__ feat,
                                          const u16* __restrict__ clsH, const u16* __restrict__ clsL,
                                          const u16* __restrict__ clsWT,
                                          const float* __restrict__ m_g, const float* __restrict__ rZ,
                                          float* __restrict__ part, float* __restrict__ out1){
  extern __shared__ char sm[];
  u16*  ftH = (u16*)(sm + K3_FTH);
  u16*  wls = (u16*)(sm + K3_FTH);   // alias: pos-weights tile [64][W_STRIDE]
  u16*  ftL = (u16*)(sm + K3_FTL);
  u16*  fN  = (u16*)(sm + K3_FN);    // [256][FN_STRIDE]
  float* S  = (float*)(sm + K3_S);
  u16*  U   = (u16*)(sm + K3_S);     // alias: normalized cls-weights [160][U_STRIDE]
  float* pm  = (float*)(sm + K3_PM);
  float* mpv = (float*)(sm + K3_MPV);
  float* ps  = (float*)(sm + K3_PS);
  float* rzp = (float*)(sm + K3_RZP);
  int b = blockIdx.x >> 5, ch = blockIdx.x & 31, t = threadIdx.x;
  const float* featG = feat + b*(CDIM*HW);
  const u16* clsHb = clsH + b*NPAD*CDIM;
  const u16* clsLb = clsL + b*NPAD*CDIM;
  const float* mgB = m_g + b*NPAD;
  const float* rZB = rZ + b*NPAD;
  int lane = t & 63, wv = t >> 6;
  int l15 = lane & 15, lk = lane >> 4;
  int cstrip = wv*32;
  int g = wv, p = lane;

  f32x4 accC[2][10];
  #pragma unroll
  for (int f = 0; f < 2; ++f)
    #pragma unroll
    for (int nf = 0; nf < 10; ++nf) accC[f][nf] = (f32x4){0.f, 0.f, 0.f, 0.f};

  for (int sub = 0; sub < 8; ++sub){
    int p0 = ch*512 + sub*64;
    stage_feat(featG, p0, ftH, ftL, fN, t);
    __syncthreads();
    s_gemm_tile(clsHb, clsLb, ftH, ftL, S, t);
    __syncthreads();
    // P2: pos (per-pixel) softmax stats over n<150
    float pmax = -3.0e38f;
    #pragma unroll
    for (int j = 0; j < 19; ++j){
      int n = g + 8*j;
      if (n < NCLS) pmax = fmaxf(pmax, S[n*S_STRIDE + p]);
    }
    pm[g*64 + p] = pmax;
    __syncthreads();
    if (t < 64){
      float mp = pm[t];
      #pragma unroll
      for (int g2 = 1; g2 < 8; ++g2) mp = fmaxf(mp, pm[g2*64 + t]);
      mpv[t] = mp;
    }
    __syncthreads();
    float mpp = mpv[p];
    float sacc = 0.f;
    #pragma unroll
    for (int j = 0; j < 19; ++j){
      int n = g + 8*j;
      if (n < NCLS) sacc += __expf(S[n*S_STRIDE + p] - mpp);
    }
    ps[g*64 + p] = sacc;
    __syncthreads();
    if (t < 64){
      float z = 0.f;
      #pragma unroll
      for (int g2 = 0; g2 < 8; ++g2) z += ps[g2*64 + t];
      rzp[t] = 1.0f / z;
    }
    __syncthreads();
    // P3a: w tile (over ftH region): w[p][n] = exp(S-mp)/Zp, 0 for pad n
    float rz = rzp[p];
    #pragma unroll
    for (int j = 0; j < 20; ++j){
      int n = g + 8*j;
      float val = 0.f;
      if (n < NCLS) val = __expf(S[n*S_STRIDE + p] - mpp) * rz;
      wls[p*W_STRIDE + n] = f2bf(val);
    }
    // P3b: U tile (over S region): U[n][p] = exp(S-m_g)/Z  (read S to regs, barrier, write)
    float uv[20];
    #pragma unroll
    for (int j = 0; j < 20; ++j){
      int n = g + 8*j;
      uv[j] = __expf(S[n*S_STRIDE + p] - mgB[n]) * rZB[n];
    }
    __syncthreads();
    #pragma unroll
    for (int j = 0; j < 20; ++j){
      int n = g + 8*j;
      U[n*U_STRIDE + p] = f2bf(uv[j]);
    }
    __syncthreads();
    // P4: cls-value partial GEMM: accC[c][n] += featN[c][p] * U[n][p]
    #pragma unroll
    for (int kb = 0; kb < 2; ++kb){
      int ko = kb*32 + lk*8;
      bf16x8 a0 = *(const bf16x8*)&fN[(cstrip + l15)*FN_STRIDE + ko];
      bf16x8 a1 = *(const bf16x8*)&fN[(cstrip + 16 + l15)*FN_STRIDE + ko];
      #pragma unroll
      for (int nf = 0; nf < 10; ++nf){
        bf16x8 bb = *(const bf16x8*)&U[(nf*16 + l15)*U_STRIDE + ko];
        accC[0][nf] = MFMA16(a0, bb, accC[0][nf], 0, 0, 0);
        accC[1][nf] = MFMA16(a1, bb, accC[1][nf], 0, 0, 0);
      }
    }
    // P5: pos-value GEMM: out[c][p] = feat[c][p] + sum_n cls_wT[c][n]*w[n][p]
    f32x4 accO[2][4];
    #pragma unroll
    for (int f = 0; f < 2; ++f)
      #pragma unroll
      for (int pf = 0; pf < 4; ++pf) accO[f][pf] = (f32x4){0.f, 0.f, 0.f, 0.f};
    #pragma unroll
    for (int kb = 0; kb < 5; ++kb){
      int ko = kb*32 + lk*8;
      bf16x8 a0 = *(const bf16x8*)&clsWT[(b*CDIM + cstrip + l15)*NPAD + ko];
      bf16x8 a1 = *(const bf16x8*)&clsWT[(b*CDIM + cstrip + 16 + l15)*NPAD + ko];
      #pragma unroll
      for (int pf = 0; pf < 4; ++pf){
        bf16x8 bb = *(const bf16x8*)&wls[(pf*16 + l15)*W_STRIDE + ko];
        accO[0][pf] = MFMA16(a0, bb, accO[0][pf], 0, 0, 0);
        accO[1][pf] = MFMA16(a1, bb, accO[1][pf], 0, 0, 0);
      }
    }
    #pragma unroll
    for (int f = 0; f < 2; ++f){
      #pragma unroll
      for (int pf = 0; pf < 4; ++pf){
        #pragma unroll
        for (int r = 0; r < 4; ++r){
          int c = cstrip + f*16 + lk*4 + r;
          int pp = pf*16 + l15;
          float fv = bff(fN[c*FN_STRIDE + pp]);
          out1[(b*CDIM + c)*HW + p0 + pp] = accO[f][pf][r] + fv;
        }
      }
    }
    __syncthreads();
  }
  // write cls partials [b][ch][c][n]
  #pragma unroll
  for (int f = 0; f < 2; ++f){
    #pragma unroll
    for (int nf = 0; nf < 10; ++nf){
      #pragma unroll
      for (int r = 0; r < 4; ++r){
        int c = cstrip + f*16 + lk*4 + r;
        int n = nf*16 + l15;
        part[((b*32 + ch)*CDIM + c)*NPAD + n] = accC[f][nf][r];
      }
    }
  }
}

// ---------------- K4: sum split-K partials, project with W_cls, add cls_repr -> out0
__global__ __launch_bounds__(256) void k4(const float* __restrict__ part, const float* __restrict__ Wc,
                                          const float* __restrict__ cls, float* __restrict__ out0){
  int b = blockIdx.x / 10, nb = blockIdx.x % 10, t = threadIdx.x;
  __shared__ float comb[256][17];
  float a16[16];
  #pragma unroll
  for (int j = 0; j < 16; ++j) a16[j] = 0.f;
  for (int s = 0; s < 32; ++s){
    const float* src = part + ((b*32 + s)*CDIM + t)*NPAD + nb*16;
    #pragma unroll
    for (int q = 0; q < 4; ++q){
      f32x4 v = *(const f32x4*)&src[q*4];
      a16[q*4+0] += v[0]; a16[q*4+1] += v[1]; a16[q*4+2] += v[2]; a16[q*4+3] += v[3];
    }
  }
  #pragma unroll
  for (int j = 0; j < 16; ++j) comb[t][j] = a16[j];
  __syncthreads();
  const float* wr = Wc + t*CDIM;
  for (int j = 0; j < 16; ++j){
    int n = nb*16 + j;
    if (n >= NCLS) break;
    float o = 0.f;
    #pragma unroll 4
    for (int c = 0; c < 256; c += 4){
      o += comb[c][j]*wr[c] + comb[c+1][j]*wr[c+1] + comb[c+2][j]*wr[c+2] + comb[c+3][j]*wr[c+3];
    }
    out0[(b*NCLS + n)*CDIM + t] = cls[(b*NCLS + n)*CDIM + t] + o;
  }
}

extern "C" void kernel_launch(void* const* d_in, const int* in_sizes, int n_in,
                              void* d_out, int out_size, void* d_ws, size_t ws_size,
                              hipStream_t stream){
  (void)in_sizes; (void)n_in; (void)out_size; (void)ws_size;
  const float* cls  = (const float*)d_in[0];   // [8][150][256]
  const float* feat = (const float*)d_in[1];   // [8][256][16384]
  const float* Wc   = (const float*)d_in[2];   // [256][256]
  const float* Wf   = (const float*)d_in[3];   // [256][256]
  float* out0 = (float*)d_out;                 // [8][150][256]
  float* out1 = out0 + 8*NCLS*CDIM;            // [8][256][16384]
  char* ws = (char*)d_ws;
  u16*  clsH  = (u16*)(ws + WS_CLSH);
  u16*  clsL  = (u16*)(ws + WS_CLSL);
  u16*  clsWT = (u16*)(ws + WS_CLSWT);
  float* ms   = (float*)(ws + WS_MS);
  float* ls   = (float*)(ws + WS_LS);
  float* mg   = (float*)(ws + WS_MG);
  float* rZ   = (float*)(ws + WS_RZ);
  float* part = (float*)(ws + WS_PART);

  hipFuncSetAttribute((const void*)k1, hipFuncAttributeMaxDynamicSharedMemorySize, K1_LDS);
  hipFuncSetAttribute((const void*)k3, hipFuncAttributeMaxDynamicSharedMemorySize, K3_LDS);

  k0<<<8*NPAD, 256, 0, stream>>>(cls, Wf, clsH, clsL, clsWT);
  k1<<<256, 512, K1_LDS, stream>>>(feat, clsH, clsL, ms, ls);
  k2<<<8, 256, 0, stream>>>(ms, ls, mg, rZ);
  k3<<<256, 512, K3_LDS, stream>>>(feat, clsH, clsL, clsWT, mg, rZ, part, out1);
  k4<<<80, 256, 0, stream>>>(part, Wc, cls, out0);
}

// Round 2
// 747.216 us; speedup vs baseline: 1.2505x; 1.2505x over previous
//
#include <hip/hip_runtime.h>

typedef unsigned short u16;
typedef __attribute__((ext_vector_type(8))) short bf16x8;
typedef __attribute__((ext_vector_type(4))) float f32x4;
typedef __attribute__((ext_vector_type(4))) unsigned short u16x4;
typedef __attribute__((ext_vector_type(8))) unsigned short u16x8;

#define MFMA16 __builtin_amdgcn_mfma_f32_16x16x32_bf16

#define HW   16384
#define NCLS 150
#define NPAD 160
#define CDIM 256

// LDS row strides: byte stride % 32 == 16 (bank-spread) and % 16 == 0 (b128-aligned)
#define FT_STRIDE 264   // shorts per featT row (64 rows)  -> 528 B
#define FN_STRIDE 72    // shorts per featN row (256 rows) -> 144 B
#define S_STRIDE  65    // floats per S row   (160 rows)   -> 260 B
#define W_STRIDE  168   // shorts per w row   (64 rows)    -> 336 B
#define U_STRIDE  72    // shorts per U row   (160 rows)   -> 144 B

// K3 LDS layout (bytes)
#define K3_FTH 0        // aliased by w tile [64][W_STRIDE] after S-GEMM
#define K3_FTL 33792    // aliased by U tile [160][U_STRIDE] after S-GEMM
#define K3_FN  67584    // [256][FN_STRIDE]
#define K3_S   104448   // f32 [160][S_STRIDE]
#define K3_PM  146048
#define K3_MPV 148096
#define K3_PS  148352
#define K3_RZP 150400
#define K3_MRUN 150656
#define K3_LRUN 151296
#define K3_FFAC 151936
#define K3_LDS  152576

// workspace offsets (bytes)
#define WS_CLSH 0
#define WS_CLSL 655360
#define WS_CLSWT 1310720
#define WS_MS   1966080   // [8][32][160] f32
#define WS_LS   2129920   // [8][32][160] f32
#define WS_WCH  2293760   // [8][32][160] f32
#define WS_PART 2457600   // [8][32][256][160] bf16 = 20,971,520 B

__device__ __forceinline__ u16 f2bf(float f){
  unsigned u = __float_as_uint(f);
  unsigned r = u + 0x7FFFu + ((u >> 16) & 1u);
  return (u16)(r >> 16);
}
__device__ __forceinline__ float bff(u16 h){
  return __uint_as_float(((unsigned)h) << 16);
}

// ---------------- K0: cls -> bf16 hi/lo (padded to 160 rows), cls_wT = (cls @ W_f^T)^T in bf16
__global__ __launch_bounds__(256) void k0(const float* __restrict__ cls, const float* __restrict__ Wf,
                                          u16* __restrict__ clsH, u16* __restrict__ clsL,
                                          u16* __restrict__ clsWT){
  int b = blockIdx.x / NPAD, n = blockIdx.x % NPAD, t = threadIdx.x;
  __shared__ float row[256];
  int bn = b*NPAD + n;
  if (n < NCLS){
    float v = cls[(b*NCLS + n)*CDIM + t];
    u16 h = f2bf(v);
    clsH[bn*CDIM + t] = h;
    clsL[bn*CDIM + t] = f2bf(v - bff(h));
    row[t] = v;
    __syncthreads();
    float acc = 0.f;
    const float* wr = Wf + t*CDIM;
    #pragma unroll 4
    for (int c = 0; c < 256; c += 4){
      acc += row[c]*wr[c] + row[c+1]*wr[c+1] + row[c+2]*wr[c+2] + row[c+3]*wr[c+3];
    }
    clsWT[(b*CDIM + t)*NPAD + n] = f2bf(acc);
  } else {
    clsH[bn*CDIM + t] = 0;
    clsL[bn*CDIM + t] = 0;
    clsWT[(b*CDIM + t)*NPAD + n] = 0;
  }
}

// stage a 256c x 64p feat subtile: featT (hi+lo, [p][c]) and featN (hi, [c][p])
__device__ __forceinline__ void stage_feat(const float* __restrict__ featG, int p0,
                                           u16* ftH, u16* ftL, u16* fN, int t){
  int p = t & 63, cg = t >> 6;
  #pragma unroll
  for (int i = 0; i < 8; ++i){
    int c0 = (i*8 + cg)*4;
    const float* g0 = featG + c0*HW + p0 + p;
    float v0 = g0[0];
    float v1 = g0[HW];
    float v2 = g0[2*HW];
    float v3 = g0[3*HW];
    u16 h0 = f2bf(v0), h1 = f2bf(v1), h2 = f2bf(v2), h3 = f2bf(v3);
    u16x4 hv = {h0, h1, h2, h3};
    *(u16x4*)&ftH[p*FT_STRIDE + c0] = hv;
    u16x4 lv = {f2bf(v0 - bff(h0)), f2bf(v1 - bff(h1)), f2bf(v2 - bff(h2)), f2bf(v3 - bff(h3))};
    *(u16x4*)&ftL[p*FT_STRIDE + c0] = lv;
    fN[(c0+0)*FN_STRIDE + p] = h0;
    fN[(c0+1)*FN_STRIDE + p] = h1;
    fN[(c0+2)*FN_STRIDE + p] = h2;
    fN[(c0+3)*FN_STRIDE + p] = h3;
  }
}

// S[160][64] = cls[160][256] x featT^T via split-precision bf16 MFMA (hh + hl + lh)
__device__ __forceinline__ void s_gemm_tile(const u16* __restrict__ clsHb, const u16* __restrict__ clsLb,
                                            const u16* ftH, const u16* ftL, float* S, int t){
  int lane = t & 63, wv = t >> 6;
  int l15 = lane & 15, lk = lane >> 4;
  int nh = wv >> 2, pq = wv & 3;
  int nbase = nh*80;
  f32x4 acc[5];
  #pragma unroll
  for (int f = 0; f < 5; ++f) acc[f] = (f32x4){0.f, 0.f, 0.f, 0.f};
  #pragma unroll
  for (int kb = 0; kb < 8; ++kb){
    int ko = kb*32 + lk*8;
    bf16x8 bh = *(const bf16x8*)&ftH[(pq*16 + l15)*FT_STRIDE + ko];
    bf16x8 bl = *(const bf16x8*)&ftL[(pq*16 + l15)*FT_STRIDE + ko];
    #pragma unroll
    for (int f = 0; f < 5; ++f){
      int ai = (nbase + f*16 + l15)*CDIM + ko;
      bf16x8 ah = *(const bf16x8*)&clsHb[ai];
      bf16x8 al = *(const bf16x8*)&clsLb[ai];
      acc[f] = MFMA16(ah, bh, acc[f], 0, 0, 0);
      acc[f] = MFMA16(ah, bl, acc[f], 0, 0, 0);
      acc[f] = MFMA16(al, bh, acc[f], 0, 0, 0);
    }
  }
  #pragma unroll
  for (int f = 0; f < 5; ++f){
    #pragma unroll
    for (int r = 0; r < 4; ++r){
      S[(nbase + f*16 + lk*4 + r)*S_STRIDE + pq*16 + l15] = acc[f][r];
    }
  }
}

// ---------------- K3: single-pass fused kernel with running cls-softmax stats
__global__ __launch_bounds__(512) void k3(const float* __restrict__ feat,
                                          const u16* __restrict__ clsH, const u16* __restrict__ clsL,
                                          const u16* __restrict__ clsWT,
                                          u16* __restrict__ part,
                                          float* __restrict__ mS, float* __restrict__ lS,
                                          float* __restrict__ out1){
  extern __shared__ char sm[];
  u16*  ftH = (u16*)(sm + K3_FTH);
  u16*  wls = (u16*)(sm + K3_FTH);   // alias: pos-weights tile [64][W_STRIDE]
  u16*  ftL = (u16*)(sm + K3_FTL);
  u16*  U   = (u16*)(sm + K3_FTL);   // alias: cls-weights tile [160][U_STRIDE]
  u16*  fN  = (u16*)(sm + K3_FN);    // [256][FN_STRIDE]
  float* S  = (float*)(sm + K3_S);
  float* pm  = (float*)(sm + K3_PM);
  float* mpv = (float*)(sm + K3_MPV);
  float* ps  = (float*)(sm + K3_PS);
  float* rzp = (float*)(sm + K3_RZP);
  float* m_run = (float*)(sm + K3_MRUN);
  float* l_run = (float*)(sm + K3_LRUN);
  float* ffac  = (float*)(sm + K3_FFAC);
  int b = blockIdx.x >> 5, ch = blockIdx.x & 31, t = threadIdx.x;
  const float* featG = feat + b*(CDIM*HW);
  const u16* clsHb = clsH + b*NPAD*CDIM;
  const u16* clsLb = clsL + b*NPAD*CDIM;
  int lane = t & 63, wv = t >> 6;
  int l15 = lane & 15, lk = lane >> 4;
  int cstrip = wv*32;
  int g = wv, p = lane;

  if (t < NPAD){ m_run[t] = -3.0e38f; l_run[t] = 0.f; }

  f32x4 accC[2][10];
  #pragma unroll
  for (int f = 0; f < 2; ++f)
    #pragma unroll
    for (int nf = 0; nf < 10; ++nf) accC[f][nf] = (f32x4){0.f, 0.f, 0.f, 0.f};
  __syncthreads();

  for (int sub = 0; sub < 8; ++sub){
    int p0 = ch*512 + sub*64;
    stage_feat(featG, p0, ftH, ftL, fN, t);
    __syncthreads();
    s_gemm_tile(clsHb, clsLb, ftH, ftL, S, t);
    __syncthreads();
    // pos (per-pixel) softmax stats over n<150
    float pmax = -3.0e38f;
    #pragma unroll
    for (int j = 0; j < 19; ++j){
      int n = g + 8*j;
      if (n < NCLS) pmax = fmaxf(pmax, S[n*S_STRIDE + p]);
    }
    pm[g*64 + p] = pmax;
    __syncthreads();
    if (t < 64){
      float mp = pm[t];
      #pragma unroll
      for (int g2 = 1; g2 < 8; ++g2) mp = fmaxf(mp, pm[g2*64 + t]);
      mpv[t] = mp;
    }
    __syncthreads();
    float mpp = mpv[p];
    float sacc = 0.f;
    #pragma unroll
    for (int j = 0; j < 19; ++j){
      int n = g + 8*j;
      if (n < NCLS) sacc += __expf(S[n*S_STRIDE + p] - mpp);
    }
    ps[g*64 + p] = sacc;
    __syncthreads();
    if (t < 64){
      float z = 0.f;
      #pragma unroll
      for (int g2 = 0; g2 < 8; ++g2) z += ps[g2*64 + t];
      rzp[t] = 1.0f / z;
    }
    __syncthreads();
    // w tile (over ftH region): w[p][n] = exp(S-mp)/Zp, 0 for pad n
    float rz = rzp[p];
    #pragma unroll
    for (int j = 0; j < 20; ++j){
      int n = g + 8*j;
      float val = 0.f;
      if (n < NCLS) val = __expf(S[n*S_STRIDE + p] - mpp) * rz;
      wls[p*W_STRIDE + n] = f2bf(val);
    }
    // running cls stats + U tile (over ftL region): U[n][p] = exp(S - m_run_new)
    if (t < NPAD){
      float m_old = m_run[t];
      const float* Sr = S + t*S_STRIDE;
      float rmax = -3.0e38f;
      #pragma unroll 8
      for (int pp = 0; pp < 64; ++pp) rmax = fmaxf(rmax, Sr[pp]);
      float mn = fmaxf(m_old, rmax);
      float fac = __expf(m_old - mn);   // 0 on first sub
      float s = 0.f;
      u16* Ur = U + t*U_STRIDE;
      #pragma unroll 4
      for (int pp = 0; pp < 64; ++pp){
        float e = __expf(Sr[pp] - mn);
        s += e;
        Ur[pp] = f2bf(e);
      }
      l_run[t] = l_run[t]*fac + s;
      m_run[t] = mn;
      ffac[t] = fac;
    }
    __syncthreads();
    // rescale accC by per-n factor
    #pragma unroll
    for (int nf = 0; nf < 10; ++nf){
      float fac = ffac[nf*16 + l15];
      #pragma unroll
      for (int f = 0; f < 2; ++f){
        accC[f][nf][0] *= fac; accC[f][nf][1] *= fac;
        accC[f][nf][2] *= fac; accC[f][nf][3] *= fac;
      }
    }
    // cls-value partial GEMM: accC[c][n] += featN[c][p] * U[n][p]
    #pragma unroll
    for (int kb = 0; kb < 2; ++kb){
      int ko = kb*32 + lk*8;
      bf16x8 a0 = *(const bf16x8*)&fN[(cstrip + l15)*FN_STRIDE + ko];
      bf16x8 a1 = *(const bf16x8*)&fN[(cstrip + 16 + l15)*FN_STRIDE + ko];
      #pragma unroll
      for (int nf = 0; nf < 10; ++nf){
        bf16x8 bb = *(const bf16x8*)&U[(nf*16 + l15)*U_STRIDE + ko];
        accC[0][nf] = MFMA16(a0, bb, accC[0][nf], 0, 0, 0);
        accC[1][nf] = MFMA16(a1, bb, accC[1][nf], 0, 0, 0);
      }
    }
    // pos-value GEMM: out1[c][p] = feat[c][p] + sum_n cls_wT[c][n]*w[n][p]
    f32x4 accO[2][4];
    #pragma unroll
    for (int f = 0; f < 2; ++f)
      #pragma unroll
      for (int pf = 0; pf < 4; ++pf) accO[f][pf] = (f32x4){0.f, 0.f, 0.f, 0.f};
    #pragma unroll
    for (int kb = 0; kb < 5; ++kb){
      int ko = kb*32 + lk*8;
      bf16x8 a0 = *(const bf16x8*)&clsWT[(b*CDIM + cstrip + l15)*NPAD + ko];
      bf16x8 a1 = *(const bf16x8*)&clsWT[(b*CDIM + cstrip + 16 + l15)*NPAD + ko];
      #pragma unroll
      for (int pf = 0; pf < 4; ++pf){
        bf16x8 bb = *(const bf16x8*)&wls[(pf*16 + l15)*W_STRIDE + ko];
        accO[0][pf] = MFMA16(a0, bb, accO[0][pf], 0, 0, 0);
        accO[1][pf] = MFMA16(a1, bb, accO[1][pf], 0, 0, 0);
      }
    }
    #pragma unroll
    for (int f = 0; f < 2; ++f){
      #pragma unroll
      for (int pf = 0; pf < 4; ++pf){
        #pragma unroll
        for (int r = 0; r < 4; ++r){
          int c = cstrip + f*16 + lk*4 + r;
          int pp = pf*16 + l15;
          float fv = bff(fN[c*FN_STRIDE + pp]);
          out1[(b*CDIM + c)*HW + p0 + pp] = accO[f][pf][r] + fv;
        }
      }
    }
    __syncthreads();
  }
  // write per-chunk partials (bf16) + chunk stats
  #pragma unroll
  for (int f = 0; f < 2; ++f){
    #pragma unroll
    for (int nf = 0; nf < 10; ++nf){
      #pragma unroll
      for (int r = 0; r < 4; ++r){
        int c = cstrip + f*16 + lk*4 + r;
        int n = nf*16 + l15;
        part[((b*32 + ch)*CDIM + c)*NPAD + n] = f2bf(accC[f][nf][r]);
      }
    }
  }
  if (t < NPAD){
    mS[(b*32 + ch)*NPAD + t] = m_run[t];
    lS[(b*32 + ch)*NPAD + t] = l_run[t];
  }
}

// ---------------- K2p: per-chunk cls-softmax weights e^{m_ch-m_g}/Z
__global__ __launch_bounds__(256) void k2p(const float* __restrict__ mS, const float* __restrict__ lS,
                                           float* __restrict__ wch){
  int b = blockIdx.x, t = threadIdx.x;
  if (t < NPAD){
    float mv[32];
    float m = -3.0e38f;
    for (int s = 0; s < 32; ++s){ mv[s] = mS[(b*32+s)*NPAD + t]; m = fmaxf(m, mv[s]); }
    float Z = 0.f;
    for (int s = 0; s < 32; ++s) Z += lS[(b*32+s)*NPAD + t] * __expf(mv[s] - m);
    float rZ = 1.0f / Z;
    for (int s = 0; s < 32; ++s) wch[(b*32+s)*NPAD + t] = __expf(mv[s] - m) * rZ;
  }
}

// ---------------- K4: weighted sum of chunk partials, project with W_cls, add cls_repr -> out0
__global__ __launch_bounds__(256) void k4(const u16* __restrict__ part, const float* __restrict__ wch,
                                          const float* __restrict__ Wc,
                                          const float* __restrict__ cls, float* __restrict__ out0){
  int b = blockIdx.x / 10, nb = blockIdx.x % 10, t = threadIdx.x;
  __shared__ float comb[256][17];
  __shared__ float wt[32][16];
  {
    int i0 = t*2;
    wt[i0>>4][i0&15] = wch[(b*32 + (i0>>4))*NPAD + nb*16 + (i0&15)];
    int i1 = i0 + 1;
    wt[i1>>4][i1&15] = wch[(b*32 + (i1>>4))*NPAD + nb*16 + (i1&15)];
  }
  __syncthreads();
  float a16[16];
  #pragma unroll
  for (int j = 0; j < 16; ++j) a16[j] = 0.f;
  for (int s = 0; s < 32; ++s){
    const u16* src = part + (size_t)((b*32+s)*CDIM + t)*NPAD + nb*16;
    u16x8 v0 = *(const u16x8*)&src[0];
    u16x8 v1 = *(const u16x8*)&src[8];
    #pragma unroll
    for (int j = 0; j < 8; ++j) a16[j] += bff(v0[j]) * wt[s][j];
    #pragma unroll
    for (int j = 0; j < 8; ++j) a16[8+j] += bff(v1[j]) * wt[s][8+j];
  }
  #pragma unroll
  for (int j = 0; j < 16; ++j) comb[t][j] = a16[j];
  __syncthreads();
  const float* wr = Wc + t*CDIM;
  for (int j = 0; j < 16; ++j){
    int n = nb*16 + j;
    if (n >= NCLS) break;
    float o = 0.f;
    #pragma unroll 4
    for (int c = 0; c < 256; c += 4){
      o += comb[c][j]*wr[c] + comb[c+1][j]*wr[c+1] + comb[c+2][j]*wr[c+2] + comb[c+3][j]*wr[c+3];
    }
    out0[(b*NCLS + n)*CDIM + t] = cls[(b*NCLS + n)*CDIM + t] + o;
  }
}

extern "C" void kernel_launch(void* const* d_in, const int* in_sizes, int n_in,
                              void* d_out, int out_size, void* d_ws, size_t ws_size,
                              hipStream_t stream){
  (void)in_sizes; (void)n_in; (void)out_size; (void)ws_size;
  const float* cls  = (const float*)d_in[0];   // [8][150][256]
  const float* feat = (const float*)d_in[1];   // [8][256][16384]
  const float* Wc   = (const float*)d_in[2];   // [256][256]
  const float* Wf   = (const float*)d_in[3];   // [256][256]
  float* out0 = (float*)d_out;                 // [8][150][256]
  float* out1 = out0 + 8*NCLS*CDIM;            // [8][256][16384]
  char* ws = (char*)d_ws;
  u16*  clsH  = (u16*)(ws + WS_CLSH);
  u16*  clsL  = (u16*)(ws + WS_CLSL);
  u16*  clsWT = (u16*)(ws + WS_CLSWT);
  float* mSv  = (float*)(ws + WS_MS);
  float* lSv  = (float*)(ws + WS_LS);
  float* wch  = (float*)(ws + WS_WCH);
  u16*  part  = (u16*)(ws + WS_PART);

  hipFuncSetAttribute((const void*)k3, hipFuncAttributeMaxDynamicSharedMemorySize, K3_LDS);

  k0<<<8*NPAD, 256, 0, stream>>>(cls, Wf, clsH, clsL, clsWT);
  k3<<<256, 512, K3_LDS, stream>>>(feat, clsH, clsL, clsWT, part, mSv, lSv, out1);
  k2p<<<8, 256, 0, stream>>>(mSv, lSv, wch);
  k4<<<80, 256, 0, stream>>>(part, wch, Wc, cls, out0);
}